// Round 13
// baseline (546.028 us; speedup 1.0000x reference)
//
#include <hip/hip_runtime.h>
#include <hip/hip_bf16.h>

#define N_NODES 100000
#define N_EDGES 1600000
#define DIM 128
#define BR 32
#define ESTG 1024   // LDS edge-stage capacity (span ~Poisson(512); fallback covers >1024)
#define NB 782      // buckets of 128 nodes
#define CHUNK 4096  // edges per binning block
#define NBLK 391    // ceil(E / CHUNK)
#define NTILE 3125  // N_NODES / BR
#define PGRID 2048  // persistent fused grid: 8 blocks/CU x 256 CUs

typedef __attribute__((ext_vector_type(8))) short bf16x8;
typedef __attribute__((ext_vector_type(4))) float f32x4;
typedef __attribute__((ext_vector_type(2))) float f32x2;
typedef __attribute__((ext_vector_type(4))) float f4;
typedef __attribute__((ext_vector_type(4))) unsigned int u32x4;
typedef __attribute__((ext_vector_type(2))) unsigned int u32x2;
typedef __attribute__((ext_vector_type(4))) int i32x4;

// ---------------- workspace layout (int units) -----------------------------
#define OFF_ROWPTR 0
#define OFF_BCNT   (N_NODES + 4)
#define OFF_BBASE  (OFF_BCNT + NB)
#define OFF_CNTM   (OFF_BBASE + NB)                 // [NBLK][NB] counts->offsets
#define OFF_PAIRS  (OFF_CNTM + NBLK * NB)
#define OFF_COLSRC (OFF_PAIRS + N_EDGES)
#define OFF_HB     (OFF_COLSRC + N_EDGES)
#define OFF_HF8    (OFF_HB + N_NODES * DIM / 2)
#define OFF_WB     (OFF_HF8 + N_NODES * DIM / 4)

// round-to-nearest-even f32 -> bf16 bits
__device__ inline unsigned int f2bf(float f) {
    unsigned int u = __float_as_uint(f);
    return (u + 0x7FFFu + ((u >> 16) & 1u)) >> 16;
}
__device__ inline unsigned char f2fp8(float v) {
    return (unsigned char)(__builtin_amdgcn_cvt_pk_fp8_f32(v, v, 0u, false) & 0xFFu);
}

// ---------------------------------------------------------------------------
// Merged streaming prep: [0,6250) x -> fp8 + bf16; [6250,6506) pack weights;
// [6506,6506+NBLK) per-chunk bucket histogram -> cntM (no global atomics).
// ---------------------------------------------------------------------------
__global__ __launch_bounds__(256) void conv_pack_kernel(
    const float* __restrict__ x, unsigned char* __restrict__ xf8,
    unsigned short* __restrict__ xb,
    const float* __restrict__ W1l, const float* __restrict__ W1r,
    const float* __restrict__ W2l, const float* __restrict__ W2r,
    unsigned short* __restrict__ WB,
    const int* __restrict__ dst, int* __restrict__ cntM)
{
    __shared__ int histL[NB];
    const int b = blockIdx.x;
    const int tid = threadIdx.x;
    if (b < 6250) {
        long i = (long)(b * 256 + tid) * 8;
        f4 a = __builtin_nontemporal_load((const f4*)(x + i));
        f4 c = __builtin_nontemporal_load((const f4*)(x + i + 4));
        unsigned int w0 = 0, w1 = 0;
        w0 = __builtin_amdgcn_cvt_pk_fp8_f32(a[0], a[1], w0, false);
        w0 = __builtin_amdgcn_cvt_pk_fp8_f32(a[2], a[3], w0, true);
        w1 = __builtin_amdgcn_cvt_pk_fp8_f32(c[0], c[1], w1, false);
        w1 = __builtin_amdgcn_cvt_pk_fp8_f32(c[2], c[3], w1, true);
        u32x2 o8; o8[0] = w0; o8[1] = w1;
        __builtin_nontemporal_store(o8, (u32x2*)(xf8 + i));
        u32x4 ob;
        ob[0] = f2bf(a[0]) | (f2bf(a[1]) << 16);
        ob[1] = f2bf(a[2]) | (f2bf(a[3]) << 16);
        ob[2] = f2bf(c[0]) | (f2bf(c[1]) << 16);
        ob[3] = f2bf(c[2]) | (f2bf(c[3]) << 16);
        __builtin_nontemporal_store(ob, (u32x4*)(xb + i));
    } else if (b < 6506) {
        int t = (b - 6250) * 256 + tid;           // < 65536
        int layer = t >> 15;
        int rest  = t & 32767;
        int half  = rest >> 14;
        int idx   = rest & 16383;
        int k = idx >> 7;
        int n = idx & 127;
        const float* W = layer ? (half ? W2r : W2l) : (half ? W1r : W1l);
        int kk = half * 128 + k;
        WB[layer * 32768 + (((kk >> 3) * 128 + n) << 3) + (kk & 7)] =
            (unsigned short)f2bf(W[idx]);
    } else {
        const int blk = b - 6506;
        const int e0 = blk * CHUNK;
        const int e1 = min(e0 + CHUNK, N_EDGES);
        for (int q = tid; q < NB; q += 256) histL[q] = 0;
        __syncthreads();
        for (int i = (e0 >> 2) + tid; i < (e1 >> 2); i += 256) {
            i32x4 d = __builtin_nontemporal_load((const i32x4*)dst + i);
            atomicAdd(&histL[d[0] >> 7], 1);
            atomicAdd(&histL[d[1] >> 7], 1);
            atomicAdd(&histL[d[2] >> 7], 1);
            atomicAdd(&histL[d[3] >> 7], 1);
        }
        __syncthreads();
        for (int q = tid; q < NB; q += 256)
            cntM[blk * NB + q] = histL[q];
    }
}

// ---------------------------------------------------------------------------
// K2a: bucket totals (column sums of cntM).
// ---------------------------------------------------------------------------
__global__ __launch_bounds__(256) void colsum_kernel(
    const int* __restrict__ cntM, int* __restrict__ bcnt)
{
    __shared__ int red[256];
    const int b = blockIdx.x;
    const int tid = threadIdx.x;
    int s = 0;
    for (int i = tid; i < NBLK; i += 256) s += cntM[i * NB + b];
    red[tid] = s;
    __syncthreads();
    for (int off = 128; off > 0; off >>= 1) {
        if (tid < off) red[tid] += red[tid + off];
        __syncthreads();
    }
    if (tid == 0) bcnt[b] = red[0];
}

// ---------------------------------------------------------------------------
// K2b: exclusive scan of bucket counts -> bbase; rowptr[N]=E.
// ---------------------------------------------------------------------------
__global__ __launch_bounds__(1024) void bscan_kernel(
    const int* __restrict__ bcnt, int* __restrict__ bbase,
    int* __restrict__ rowptr)
{
    __shared__ int tmp[1024];
    int tid = threadIdx.x;
    int v = (tid < NB) ? bcnt[tid] : 0;
    tmp[tid] = v;
    __syncthreads();
    for (int off = 1; off < 1024; off <<= 1) {
        int t = (tid >= off) ? tmp[tid - off] : 0;
        __syncthreads();
        tmp[tid] += t;
        __syncthreads();
    }
    if (tid < NB) bbase[tid] = tmp[tid] - v;
    if (tid == 0) rowptr[N_NODES] = N_EDGES;
}

// ---------------------------------------------------------------------------
// K2c: per-bucket prefix over blocks: cntM[i][b] -> bbase[b] + excl prefix
// (in place). One block per bucket; 2-elem/thread Hillis-Steele over 512.
// ---------------------------------------------------------------------------
__global__ __launch_bounds__(256) void colprefix_kernel(
    int* __restrict__ cntM, const int* __restrict__ bbase)
{
    __shared__ int e0[512];
    __shared__ int tmp[256];
    const int b = blockIdx.x;
    const int tid = threadIdx.x;
    int a0 = (2 * tid     < NBLK) ? cntM[(2 * tid)     * NB + b] : 0;
    int a1 = (2 * tid + 1 < NBLK) ? cntM[(2 * tid + 1) * NB + b] : 0;
    tmp[tid] = a0 + a1;
    __syncthreads();
    for (int off = 1; off < 256; off <<= 1) {
        int t = (tid >= off) ? tmp[tid - off] : 0;
        __syncthreads();
        tmp[tid] += t;
        __syncthreads();
    }
    int ex = tmp[tid] - (a0 + a1);
    e0[2 * tid] = ex;
    e0[2 * tid + 1] = ex + a0;
    __syncthreads();
    const int base = bbase[b];
    if (2 * tid < NBLK)     cntM[(2 * tid)     * NB + b] = base + e0[2 * tid];
    if (2 * tid + 1 < NBLK) cntM[(2 * tid + 1) * NB + b] = base + e0[2 * tid + 1];
}

// ---------------------------------------------------------------------------
// K3: single-pass binning: LDS rank + precomputed offsets (no global atomics).
// ---------------------------------------------------------------------------
__global__ __launch_bounds__(256) void bfill_kernel(
    const int* __restrict__ src, const int* __restrict__ dst,
    const int* __restrict__ cntM, unsigned int* __restrict__ pairs)
{
    __shared__ int histL[NB];
    __shared__ int baseL[NB];
    const int tid = threadIdx.x;
    const int blk = blockIdx.x;
    const int e0 = blk * CHUNK;
    const int e1 = min(e0 + CHUNK, N_EDGES);
    for (int b = tid; b < NB; b += 256) {
        baseL[b] = cntM[blk * NB + b];
        histL[b] = 0;
    }
    __syncthreads();
    for (int i = (e0 >> 2) + tid; i < (e1 >> 2); i += 256) {
        i32x4 s = __builtin_nontemporal_load((const i32x4*)src + i);
        i32x4 d = __builtin_nontemporal_load((const i32x4*)dst + i);
        #pragma unroll
        for (int k = 0; k < 4; ++k) {
            int bk = d[k] >> 7;
            int r = atomicAdd(&histL[bk], 1);
            pairs[baseL[bk] + r] =
                (unsigned int)s[k] | ((unsigned int)(d[k] & 127) << 25);
        }
    }
}

// ---------------------------------------------------------------------------
// K4: per-bucket exact CSR (128-node LDS hist + scan + LDS tickets).
// ---------------------------------------------------------------------------
__global__ __launch_bounds__(256) void bucket_csr_kernel(
    const unsigned int* __restrict__ pairs,
    const int* __restrict__ bcnt, const int* __restrict__ bbase,
    int* __restrict__ rowptr, int* __restrict__ colsrc)
{
    __shared__ int histA[128], exclS[128], hist2[128];
    const int bucket = blockIdx.x;
    const int tid = threadIdx.x;
    const int cnt  = bcnt[bucket];
    const int base = bbase[bucket];
    if (tid < 128) { histA[tid] = 0; hist2[tid] = 0; }
    __syncthreads();
    for (int i = tid; i < cnt; i += 256)
        atomicAdd(&histA[pairs[base + i] >> 25], 1);
    __syncthreads();
    int v = 0;
    if (tid < 128) { v = histA[tid]; exclS[tid] = v; }
    __syncthreads();
    for (int off = 1; off < 128; off <<= 1) {
        int t = 0;
        if (tid < 128 && tid >= off) t = exclS[tid - off];
        __syncthreads();
        if (tid < 128) exclS[tid] += t;
        __syncthreads();
    }
    if (tid < 128) exclS[tid] -= v;    // exclusive
    const int node0 = bucket * 128;
    if (tid < 128 && node0 + tid < N_NODES)
        rowptr[node0 + tid] = base + exclS[tid];
    __syncthreads();
    for (int i = tid; i < cnt; i += 256) {
        unsigned int p = pairs[base + i];
        int dl = (int)(p >> 25);
        int r = atomicAdd(&hist2[dl], 1);
        colsrc[base + exclS[dl] + r] = (int)(p & 0x1FFFFFFu);
    }
}

// ---------------------------------------------------------------------------
// Fused SAGE layer (r12 structure + PERSISTENT GRID): 2048 co-resident
// blocks grid-stride over 3125 tiles -> no dispatch tail, max MLP.
// ---------------------------------------------------------------------------
__device__ inline void addfp8(float* acc, u32x2 v) {
    f32x2 p;
    p = __builtin_amdgcn_cvt_pk_f32_fp8((int)v[0], false); acc[0] += p[0]; acc[1] += p[1];
    p = __builtin_amdgcn_cvt_pk_f32_fp8((int)v[0], true);  acc[2] += p[0]; acc[3] += p[1];
    p = __builtin_amdgcn_cvt_pk_f32_fp8((int)v[1], false); acc[4] += p[0]; acc[5] += p[1];
    p = __builtin_amdgcn_cvt_pk_f32_fp8((int)v[1], true);  acc[6] += p[0]; acc[7] += p[1];
}

__global__ __launch_bounds__(256, 8) void fused_sage_kernel(
    const unsigned char* __restrict__ f8,      // fp8 gather table [N][128]
    const unsigned short* __restrict__ selfB,  // bf16 self rows [N][128]
    const int* __restrict__ rowptr,
    const int* __restrict__ colsrc,
    const unsigned short* __restrict__ WB,     // fragment-major [256][128] bf16
    const float* __restrict__ bias,
    unsigned short* __restrict__ outb,         // mode 1: bf16 out (relu)
    unsigned char* __restrict__ outf8,         // mode 1: fp8 out (relu)
    float* __restrict__ outf,                  // mode 0: f32 out
    int mode)
{
    __shared__ __align__(16) char smem[20480]; // 16 KB catS + 4 KB eS
    unsigned short* catS = (unsigned short*)smem;  // [32][256] bf16, XOR swizzle
    int* eS = (int*)(smem + 16384);                // [1024] edge byte-offsets

    const int tid = threadIdx.x;
    const int c   = tid & 15;                  // slot within row
    const int c8  = c * 8;
    const int grp = tid >> 4;                  // 16 gather groups
    const int w    = tid >> 6;
    const int l    = tid & 63;
    const int wm   = w & 1;
    const int wn   = w >> 1;
    const int lrow = l & 15;
    const int kgrp = l >> 4;
    const int ar   = wm * 16 + lrow;
    const int cbase = wn * 64 + lrow;

    for (int tile = blockIdx.x; tile < NTILE; tile += PGRID) {
    const int block_row = tile * BR;
    const int ebase = rowptr[block_row];
    const int span  = rowptr[block_row + BR] - ebase;
    const int smax  = span < ESTG ? span : ESTG;

    for (int i = tid; i < smax; i += 256)
        eS[i] = __builtin_nontemporal_load(&colsrc[ebase + i]) << 7;
    __syncthreads();

    #pragma unroll
    for (int it = 0; it < 2; ++it) {
        const int nl = grp * 2 + it;
        const int node = block_row + nl;
        const int s  = rowptr[node] - ebase;
        const int e_ = rowptr[node + 1] - ebase;
        const int lim = e_ < ESTG ? e_ : ESTG;

        // self row (bf16): issue early, consumed at the end
        const u32x4 sv = __builtin_nontemporal_load(
            (const u32x4*)(selfB + ((long)node << 7) + c8));

        float acc[8];
        #pragma unroll
        for (int q = 0; q < 8; ++q) acc[q] = 0.0f;

        int i = s;
        for (; i + 8 <= lim; i += 8) {
            const u32x2 v0 = *(const u32x2*)(f8 + eS[i + 0] + c8);
            const u32x2 v1 = *(const u32x2*)(f8 + eS[i + 1] + c8);
            const u32x2 v2 = *(const u32x2*)(f8 + eS[i + 2] + c8);
            const u32x2 v3 = *(const u32x2*)(f8 + eS[i + 3] + c8);
            const u32x2 v4 = *(const u32x2*)(f8 + eS[i + 4] + c8);
            const u32x2 v5 = *(const u32x2*)(f8 + eS[i + 5] + c8);
            const u32x2 v6 = *(const u32x2*)(f8 + eS[i + 6] + c8);
            const u32x2 v7 = *(const u32x2*)(f8 + eS[i + 7] + c8);
            addfp8(acc, v0); addfp8(acc, v1); addfp8(acc, v2); addfp8(acc, v3);
            addfp8(acc, v4); addfp8(acc, v5); addfp8(acc, v6); addfp8(acc, v7);
        }
        if (i + 4 <= lim) {
            const u32x2 v0 = *(const u32x2*)(f8 + eS[i + 0] + c8);
            const u32x2 v1 = *(const u32x2*)(f8 + eS[i + 1] + c8);
            const u32x2 v2 = *(const u32x2*)(f8 + eS[i + 2] + c8);
            const u32x2 v3 = *(const u32x2*)(f8 + eS[i + 3] + c8);
            addfp8(acc, v0); addfp8(acc, v1); addfp8(acc, v2); addfp8(acc, v3);
            i += 4;
        }
        if (i + 2 <= lim) {
            const u32x2 v0 = *(const u32x2*)(f8 + eS[i + 0] + c8);
            const u32x2 v1 = *(const u32x2*)(f8 + eS[i + 1] + c8);
            addfp8(acc, v0); addfp8(acc, v1);
            i += 2;
        }
        if (i < lim) {
            const u32x2 v = *(const u32x2*)(f8 + eS[i] + c8);
            addfp8(acc, v);
            ++i;
        }
        for (; i < e_; ++i) {   // span > ESTG fallback
            const u32x2 v = *(const u32x2*)(f8 + ((long)colsrc[ebase + i] << 7) + c8);
            addfp8(acc, v);
        }

        const float inv = 1.0f / fmaxf((float)(e_ - s), 1.0f);
        uint4 pv;
        pv.x = f2bf(acc[0] * inv) | (f2bf(acc[1] * inv) << 16);
        pv.y = f2bf(acc[2] * inv) | (f2bf(acc[3] * inv) << 16);
        pv.z = f2bf(acc[4] * inv) | (f2bf(acc[5] * inv) << 16);
        pv.w = f2bf(acc[6] * inv) | (f2bf(acc[7] * inv) << 16);
        const int sw = c ^ (nl & 7);
        *(uint4*)&catS[nl * 256 + sw * 8] = pv;                      // agg
        *(u32x4*)&catS[nl * 256 + 128 + sw * 8] = sv;                // self
    }
    __syncthreads();

    // ---- MFMA GEMM: [32,256] @ [256,128] ----
    f32x4 acc4[4];
    #pragma unroll
    for (int t = 0; t < 4; ++t) acc4[t] = (f32x4){0.f, 0.f, 0.f, 0.f};

    #pragma unroll
    for (int step = 0; step < 8; ++step) {
        const int slot = step * 4 + kgrp;
        bf16x8 a = *(const bf16x8*)&catS[ar * 256 + ((slot ^ (ar & 7)) << 3)];
        #pragma unroll
        for (int t = 0; t < 4; ++t) {
            const int n = wn * 64 + t * 16 + lrow;
            bf16x8 b = *(const bf16x8*)(WB + ((slot * 128 + n) << 3));
            acc4[t] = __builtin_amdgcn_mfma_f32_16x16x32_bf16(a, b, acc4[t], 0, 0, 0);
        }
    }

    // ---- epilogue: bank-padded LDS restage + coalesced stores ----
    __syncthreads();   // all MFMA reads of catS done
    if (mode) {
        unsigned short* lbf = (unsigned short*)smem;            // [32][132] pad
        unsigned char*  lr8 = (unsigned char*)(smem + 8448);    // [32][136] pad
        #pragma unroll
        for (int t = 0; t < 4; ++t) {
            const int col = cbase + t * 16;
            const float bb = bias[col];
            #pragma unroll
            for (int j = 0; j < 4; ++j) {
                float v = fmaxf(acc4[t][j] + bb, 0.0f);
                const int row = wm * 16 + kgrp * 4 + j;
                lbf[row * 132 + col] = (unsigned short)f2bf(v);
                lr8[row * 136 + col] = f2fp8(v);
            }
        }
        __syncthreads();
        #pragma unroll
        for (int it = 0; it < 8; ++it) {
            const int row = w * 8 + it;
            unsigned int v = *(const unsigned int*)&lbf[row * 132 + l * 2];
            *(unsigned int*)&outb[(long)(block_row + row) * 128 + l * 2] = v;
        }
        #pragma unroll
        for (int it = 0; it < 4; ++it) {
            const int row = w * 8 + it * 2 + (l >> 5);
            unsigned int v = *(const unsigned int*)&lr8[row * 136 + (l & 31) * 4];
            *(unsigned int*)&outf8[(long)(block_row + row) * 128 + (l & 31) * 4] = v;
        }
    } else {
        float* lf = (float*)smem;                               // [32][132] pad
        #pragma unroll
        for (int t = 0; t < 4; ++t) {
            const int col = cbase + t * 16;
            const float bb = bias[col];
            #pragma unroll
            for (int j = 0; j < 4; ++j) {
                const int row = wm * 16 + kgrp * 4 + j;
                lf[row * 132 + col] = acc4[t][j] + bb;
            }
        }
        __syncthreads();
        #pragma unroll
        for (int it = 0; it < 16; ++it) {
            const int row  = w * 8 + (it >> 1);
            const int half = (it & 1) * 64;
            float v = lf[row * 132 + half + l];
            outf[(long)(block_row + row) * 128 + half + l] = v;
        }
    }
    __syncthreads();   // protect smem reuse across tiles
    }  // tile loop
}

// ---------------------------------------------------------------------------
extern "C" void kernel_launch(void* const* d_in, const int* in_sizes, int n_in,
                              void* d_out, int out_size, void* d_ws, size_t ws_size,
                              hipStream_t stream)
{
    const float* x   = (const float*)d_in[0];
    const int*   ei  = (const int*)d_in[1];
    const float* W1l = (const float*)d_in[2];
    const float* b1  = (const float*)d_in[3];
    const float* W1r = (const float*)d_in[4];
    const float* W2l = (const float*)d_in[5];
    const float* b2  = (const float*)d_in[6];
    const float* W2r = (const float*)d_in[7];
    float* out = (float*)d_out;

    const int* src = ei;
    const int* dst = ei + N_EDGES;

    int* wsi = (int*)d_ws;
    int* rowptr = wsi + OFF_ROWPTR;
    int* bcnt   = wsi + OFF_BCNT;
    int* bbase  = wsi + OFF_BBASE;
    int* cntM   = wsi + OFF_CNTM;
    unsigned int* pairs = (unsigned int*)(wsi + OFF_PAIRS);
    int* colsrc = wsi + OFF_COLSRC;
    unsigned short* hb  = (unsigned short*)(wsi + OFF_HB);
    unsigned char*  hf8 = (unsigned char*)(wsi + OFF_HF8);
    unsigned short* WB  = (unsigned short*)(wsi + OFF_WB);

    // xf8 (12.8MB) + xb (25.6MB) live in d_out (51.2MB), dead before layer-2
    // overwrites d_out with the f32 output.
    unsigned char*  xf8 = (unsigned char*)d_out;
    unsigned short* xb  = (unsigned short*)(xf8 + (size_t)N_NODES * DIM);

    conv_pack_kernel<<<6506 + NBLK, 256, 0, stream>>>(
        x, xf8, xb, W1l, W1r, W2l, W2r, WB, dst, cntM);
    colsum_kernel<<<NB, 256, 0, stream>>>(cntM, bcnt);
    bscan_kernel<<<1, 1024, 0, stream>>>(bcnt, bbase, rowptr);
    colprefix_kernel<<<NB, 256, 0, stream>>>(cntM, bbase);
    bfill_kernel<<<NBLK, 256, 0, stream>>>(src, dst, cntM, pairs);
    bucket_csr_kernel<<<NB, 256, 0, stream>>>(pairs, bcnt, bbase, rowptr, colsrc);

    // layer 1: gather fp8(x), self bf16 x -> hb bf16 + hf8 fp8 (relu)
    fused_sage_kernel<<<PGRID, 256, 0, stream>>>(
        xf8, xb, rowptr, colsrc, WB, b1, hb, hf8, (float*)nullptr, 1);
    // layer 2: gather fp8(h), self bf16 h -> out f32
    fused_sage_kernel<<<PGRID, 256, 0, stream>>>(
        hf8, hb, rowptr, colsrc, WB + 32768, b2,
        (unsigned short*)nullptr, (unsigned char*)nullptr, out, 0);
}

// Round 14
// 269.299 us; speedup vs baseline: 2.0276x; 2.0276x over previous
//
#include <hip/hip_runtime.h>
#include <hip/hip_bf16.h>

#define N_NODES 100000
#define N_EDGES 1600000
#define DIM 128
#define BR 32
#define ESTG 1024   // LDS edge-stage capacity (span ~Poisson(512); fallback covers >1024)
#define NB 782      // buckets of 128 nodes
#define CHUNK 4096  // edges per binning block
#define NBLK 391    // ceil(E / CHUNK)
#define NTILE 3125  // N_NODES / BR
#define PGRID 2048  // persistent fused grid: 8 blocks/CU x 256 CUs

typedef __attribute__((ext_vector_type(8))) short bf16x8;
typedef __attribute__((ext_vector_type(4))) float f32x4;
typedef __attribute__((ext_vector_type(2))) float f32x2;
typedef __attribute__((ext_vector_type(4))) float f4;
typedef __attribute__((ext_vector_type(4))) unsigned int u32x4;
typedef __attribute__((ext_vector_type(2))) unsigned int u32x2;
typedef __attribute__((ext_vector_type(4))) int i32x4;

// ---------------- workspace layout (int units) -----------------------------
#define OFF_ROWPTR 0
#define OFF_BCNT   (N_NODES + 4)
#define OFF_BBASE  (OFF_BCNT + NB)
#define OFF_CNTM   (OFF_BBASE + NB)                 // [NBLK][NB] counts->offsets
#define OFF_PAIRS  (OFF_CNTM + NBLK * NB)
#define OFF_COLSRC (OFF_PAIRS + N_EDGES)
#define OFF_HB     (OFF_COLSRC + N_EDGES)
#define OFF_HF8    (OFF_HB + N_NODES * DIM / 2)
#define OFF_WB     (OFF_HF8 + N_NODES * DIM / 4)

// round-to-nearest-even f32 -> bf16 bits
__device__ inline unsigned int f2bf(float f) {
    unsigned int u = __float_as_uint(f);
    return (u + 0x7FFFu + ((u >> 16) & 1u)) >> 16;
}
__device__ inline unsigned char f2fp8(float v) {
    return (unsigned char)(__builtin_amdgcn_cvt_pk_fp8_f32(v, v, 0u, false) & 0xFFu);
}

// ---------------------------------------------------------------------------
// Merged streaming prep: [0,6250) x -> fp8 + bf16; [6250,6506) pack weights;
// [6506,6506+NBLK) per-chunk bucket histogram -> cntM (no global atomics).
// ---------------------------------------------------------------------------
__global__ __launch_bounds__(256) void conv_pack_kernel(
    const float* __restrict__ x, unsigned char* __restrict__ xf8,
    unsigned short* __restrict__ xb,
    const float* __restrict__ W1l, const float* __restrict__ W1r,
    const float* __restrict__ W2l, const float* __restrict__ W2r,
    unsigned short* __restrict__ WB,
    const int* __restrict__ dst, int* __restrict__ cntM)
{
    __shared__ int histL[NB];
    const int b = blockIdx.x;
    const int tid = threadIdx.x;
    if (b < 6250) {
        long i = (long)(b * 256 + tid) * 8;
        f4 a = __builtin_nontemporal_load((const f4*)(x + i));
        f4 c = __builtin_nontemporal_load((const f4*)(x + i + 4));
        unsigned int w0 = 0, w1 = 0;
        w0 = __builtin_amdgcn_cvt_pk_fp8_f32(a[0], a[1], w0, false);
        w0 = __builtin_amdgcn_cvt_pk_fp8_f32(a[2], a[3], w0, true);
        w1 = __builtin_amdgcn_cvt_pk_fp8_f32(c[0], c[1], w1, false);
        w1 = __builtin_amdgcn_cvt_pk_fp8_f32(c[2], c[3], w1, true);
        u32x2 o8; o8[0] = w0; o8[1] = w1;
        __builtin_nontemporal_store(o8, (u32x2*)(xf8 + i));
        u32x4 ob;
        ob[0] = f2bf(a[0]) | (f2bf(a[1]) << 16);
        ob[1] = f2bf(a[2]) | (f2bf(a[3]) << 16);
        ob[2] = f2bf(c[0]) | (f2bf(c[1]) << 16);
        ob[3] = f2bf(c[2]) | (f2bf(c[3]) << 16);
        __builtin_nontemporal_store(ob, (u32x4*)(xb + i));
    } else if (b < 6506) {
        int t = (b - 6250) * 256 + tid;           // < 65536
        int layer = t >> 15;
        int rest  = t & 32767;
        int half  = rest >> 14;
        int idx   = rest & 16383;
        int k = idx >> 7;
        int n = idx & 127;
        const float* W = layer ? (half ? W2r : W2l) : (half ? W1r : W1l);
        int kk = half * 128 + k;
        WB[layer * 32768 + (((kk >> 3) * 128 + n) << 3) + (kk & 7)] =
            (unsigned short)f2bf(W[idx]);
    } else {
        const int blk = b - 6506;
        const int e0 = blk * CHUNK;
        const int e1 = min(e0 + CHUNK, N_EDGES);
        for (int q = tid; q < NB; q += 256) histL[q] = 0;
        __syncthreads();
        for (int i = (e0 >> 2) + tid; i < (e1 >> 2); i += 256) {
            i32x4 d = __builtin_nontemporal_load((const i32x4*)dst + i);
            atomicAdd(&histL[d[0] >> 7], 1);
            atomicAdd(&histL[d[1] >> 7], 1);
            atomicAdd(&histL[d[2] >> 7], 1);
            atomicAdd(&histL[d[3] >> 7], 1);
        }
        __syncthreads();
        for (int q = tid; q < NB; q += 256)
            cntM[blk * NB + q] = histL[q];
    }
}

// ---------------------------------------------------------------------------
// K2a: bucket totals (column sums of cntM).
// ---------------------------------------------------------------------------
__global__ __launch_bounds__(256) void colsum_kernel(
    const int* __restrict__ cntM, int* __restrict__ bcnt)
{
    __shared__ int red[256];
    const int b = blockIdx.x;
    const int tid = threadIdx.x;
    int s = 0;
    for (int i = tid; i < NBLK; i += 256) s += cntM[i * NB + b];
    red[tid] = s;
    __syncthreads();
    for (int off = 128; off > 0; off >>= 1) {
        if (tid < off) red[tid] += red[tid + off];
        __syncthreads();
    }
    if (tid == 0) bcnt[b] = red[0];
}

// ---------------------------------------------------------------------------
// K2b: exclusive scan of bucket counts -> bbase; rowptr[N]=E.
// ---------------------------------------------------------------------------
__global__ __launch_bounds__(1024) void bscan_kernel(
    const int* __restrict__ bcnt, int* __restrict__ bbase,
    int* __restrict__ rowptr)
{
    __shared__ int tmp[1024];
    int tid = threadIdx.x;
    int v = (tid < NB) ? bcnt[tid] : 0;
    tmp[tid] = v;
    __syncthreads();
    for (int off = 1; off < 1024; off <<= 1) {
        int t = (tid >= off) ? tmp[tid - off] : 0;
        __syncthreads();
        tmp[tid] += t;
        __syncthreads();
    }
    if (tid < NB) bbase[tid] = tmp[tid] - v;
    if (tid == 0) rowptr[N_NODES] = N_EDGES;
}

// ---------------------------------------------------------------------------
// K2c: per-bucket prefix over blocks: cntM[i][b] -> bbase[b] + excl prefix.
// ---------------------------------------------------------------------------
__global__ __launch_bounds__(256) void colprefix_kernel(
    int* __restrict__ cntM, const int* __restrict__ bbase)
{
    __shared__ int e0[512];
    __shared__ int tmp[256];
    const int b = blockIdx.x;
    const int tid = threadIdx.x;
    int a0 = (2 * tid     < NBLK) ? cntM[(2 * tid)     * NB + b] : 0;
    int a1 = (2 * tid + 1 < NBLK) ? cntM[(2 * tid + 1) * NB + b] : 0;
    tmp[tid] = a0 + a1;
    __syncthreads();
    for (int off = 1; off < 256; off <<= 1) {
        int t = (tid >= off) ? tmp[tid - off] : 0;
        __syncthreads();
        tmp[tid] += t;
        __syncthreads();
    }
    int ex = tmp[tid] - (a0 + a1);
    e0[2 * tid] = ex;
    e0[2 * tid + 1] = ex + a0;
    __syncthreads();
    const int base = bbase[b];
    if (2 * tid < NBLK)     cntM[(2 * tid)     * NB + b] = base + e0[2 * tid];
    if (2 * tid + 1 < NBLK) cntM[(2 * tid + 1) * NB + b] = base + e0[2 * tid + 1];
}

// ---------------------------------------------------------------------------
// K3: single-pass binning: LDS rank + precomputed offsets (no global atomics).
// ---------------------------------------------------------------------------
__global__ __launch_bounds__(256) void bfill_kernel(
    const int* __restrict__ src, const int* __restrict__ dst,
    const int* __restrict__ cntM, unsigned int* __restrict__ pairs)
{
    __shared__ int histL[NB];
    __shared__ int baseL[NB];
    const int tid = threadIdx.x;
    const int blk = blockIdx.x;
    const int e0 = blk * CHUNK;
    const int e1 = min(e0 + CHUNK, N_EDGES);
    for (int b = tid; b < NB; b += 256) {
        baseL[b] = cntM[blk * NB + b];
        histL[b] = 0;
    }
    __syncthreads();
    for (int i = (e0 >> 2) + tid; i < (e1 >> 2); i += 256) {
        i32x4 s = __builtin_nontemporal_load((const i32x4*)src + i);
        i32x4 d = __builtin_nontemporal_load((const i32x4*)dst + i);
        #pragma unroll
        for (int k = 0; k < 4; ++k) {
            int bk = d[k] >> 7;
            int r = atomicAdd(&histL[bk], 1);
            pairs[baseL[bk] + r] =
                (unsigned int)s[k] | ((unsigned int)(d[k] & 127) << 25);
        }
    }
}

// ---------------------------------------------------------------------------
// K4: per-bucket exact CSR (128-node LDS hist + scan + LDS tickets).
// ---------------------------------------------------------------------------
__global__ __launch_bounds__(256) void bucket_csr_kernel(
    const unsigned int* __restrict__ pairs,
    const int* __restrict__ bcnt, const int* __restrict__ bbase,
    int* __restrict__ rowptr, int* __restrict__ colsrc)
{
    __shared__ int histA[128], exclS[128], hist2[128];
    const int bucket = blockIdx.x;
    const int tid = threadIdx.x;
    const int cnt  = bcnt[bucket];
    const int base = bbase[bucket];
    if (tid < 128) { histA[tid] = 0; hist2[tid] = 0; }
    __syncthreads();
    for (int i = tid; i < cnt; i += 256)
        atomicAdd(&histA[pairs[base + i] >> 25], 1);
    __syncthreads();
    int v = 0;
    if (tid < 128) { v = histA[tid]; exclS[tid] = v; }
    __syncthreads();
    for (int off = 1; off < 128; off <<= 1) {
        int t = 0;
        if (tid < 128 && tid >= off) t = exclS[tid - off];
        __syncthreads();
        if (tid < 128) exclS[tid] += t;
        __syncthreads();
    }
    if (tid < 128) exclS[tid] -= v;    // exclusive
    const int node0 = bucket * 128;
    if (tid < 128 && node0 + tid < N_NODES)
        rowptr[node0 + tid] = base + exclS[tid];
    __syncthreads();
    for (int i = tid; i < cnt; i += 256) {
        unsigned int p = pairs[base + i];
        int dl = (int)(p >> 25);
        int r = atomicAdd(&hist2[dl], 1);
        colsrc[base + exclS[dl] + r] = (int)(p & 0x1FFFFFFu);
    }
}

// ---------------------------------------------------------------------------
// Per-tile fused SAGE body (r12-identical), __noinline__ so register
// allocation is function-local: the persistent caller's loop backedge
// carries only the tile index -> no cross-tile spills (r13 pathology).
// ---------------------------------------------------------------------------
__device__ inline void addfp8(float* acc, u32x2 v) {
    f32x2 p;
    p = __builtin_amdgcn_cvt_pk_f32_fp8((int)v[0], false); acc[0] += p[0]; acc[1] += p[1];
    p = __builtin_amdgcn_cvt_pk_f32_fp8((int)v[0], true);  acc[2] += p[0]; acc[3] += p[1];
    p = __builtin_amdgcn_cvt_pk_f32_fp8((int)v[1], false); acc[4] += p[0]; acc[5] += p[1];
    p = __builtin_amdgcn_cvt_pk_f32_fp8((int)v[1], true);  acc[6] += p[0]; acc[7] += p[1];
}

__device__ __attribute__((noinline)) void process_tile(
    int tile, char* smem,
    const unsigned char* __restrict__ f8,
    const unsigned short* __restrict__ selfB,
    const int* __restrict__ rowptr,
    const int* __restrict__ colsrc,
    const unsigned short* __restrict__ WB,
    const float* __restrict__ bias,
    unsigned short* __restrict__ outb,
    unsigned char* __restrict__ outf8,
    float* __restrict__ outf,
    int mode)
{
    unsigned short* catS = (unsigned short*)smem;  // [32][256] bf16, XOR swizzle
    int* eS = (int*)(smem + 16384);                // [1024] edge byte-offsets

    const int tid = threadIdx.x;
    const int block_row = tile * BR;
    const int ebase = rowptr[block_row];
    const int span  = rowptr[block_row + BR] - ebase;
    const int smax  = span < ESTG ? span : ESTG;

    for (int i = tid; i < smax; i += 256)
        eS[i] = __builtin_nontemporal_load(&colsrc[ebase + i]) << 7;
    __syncthreads();

    const int c   = tid & 15;                  // slot within row
    const int c8  = c * 8;
    const int grp = tid >> 4;                  // 16 gather groups

    #pragma unroll
    for (int it = 0; it < 2; ++it) {
        const int nl = grp * 2 + it;
        const int node = block_row + nl;
        const int s  = rowptr[node] - ebase;
        const int e_ = rowptr[node + 1] - ebase;
        const int lim = e_ < ESTG ? e_ : ESTG;

        // self row (bf16): issue early, consumed at the end
        const u32x4 sv = __builtin_nontemporal_load(
            (const u32x4*)(selfB + ((long)node << 7) + c8));

        float acc[8];
        #pragma unroll
        for (int q = 0; q < 8; ++q) acc[q] = 0.0f;

        int i = s;
        for (; i + 8 <= lim; i += 8) {
            const u32x2 v0 = *(const u32x2*)(f8 + eS[i + 0] + c8);
            const u32x2 v1 = *(const u32x2*)(f8 + eS[i + 1] + c8);
            const u32x2 v2 = *(const u32x2*)(f8 + eS[i + 2] + c8);
            const u32x2 v3 = *(const u32x2*)(f8 + eS[i + 3] + c8);
            const u32x2 v4 = *(const u32x2*)(f8 + eS[i + 4] + c8);
            const u32x2 v5 = *(const u32x2*)(f8 + eS[i + 5] + c8);
            const u32x2 v6 = *(const u32x2*)(f8 + eS[i + 6] + c8);
            const u32x2 v7 = *(const u32x2*)(f8 + eS[i + 7] + c8);
            addfp8(acc, v0); addfp8(acc, v1); addfp8(acc, v2); addfp8(acc, v3);
            addfp8(acc, v4); addfp8(acc, v5); addfp8(acc, v6); addfp8(acc, v7);
        }
        if (i + 4 <= lim) {
            const u32x2 v0 = *(const u32x2*)(f8 + eS[i + 0] + c8);
            const u32x2 v1 = *(const u32x2*)(f8 + eS[i + 1] + c8);
            const u32x2 v2 = *(const u32x2*)(f8 + eS[i + 2] + c8);
            const u32x2 v3 = *(const u32x2*)(f8 + eS[i + 3] + c8);
            addfp8(acc, v0); addfp8(acc, v1); addfp8(acc, v2); addfp8(acc, v3);
            i += 4;
        }
        if (i + 2 <= lim) {
            const u32x2 v0 = *(const u32x2*)(f8 + eS[i + 0] + c8);
            const u32x2 v1 = *(const u32x2*)(f8 + eS[i + 1] + c8);
            addfp8(acc, v0); addfp8(acc, v1);
            i += 2;
        }
        if (i < lim) {
            const u32x2 v = *(const u32x2*)(f8 + eS[i] + c8);
            addfp8(acc, v);
            ++i;
        }
        for (; i < e_; ++i) {   // span > ESTG fallback
            const u32x2 v = *(const u32x2*)(f8 + ((long)colsrc[ebase + i] << 7) + c8);
            addfp8(acc, v);
        }

        const float inv = 1.0f / fmaxf((float)(e_ - s), 1.0f);
        uint4 pv;
        pv.x = f2bf(acc[0] * inv) | (f2bf(acc[1] * inv) << 16);
        pv.y = f2bf(acc[2] * inv) | (f2bf(acc[3] * inv) << 16);
        pv.z = f2bf(acc[4] * inv) | (f2bf(acc[5] * inv) << 16);
        pv.w = f2bf(acc[6] * inv) | (f2bf(acc[7] * inv) << 16);
        const int sw = c ^ (nl & 7);
        *(uint4*)&catS[nl * 256 + sw * 8] = pv;                      // agg
        *(u32x4*)&catS[nl * 256 + 128 + sw * 8] = sv;                // self
    }
    __syncthreads();

    // ---- MFMA GEMM: [32,256] @ [256,128] ----
    const int w    = tid >> 6;
    const int l    = tid & 63;
    const int wm   = w & 1;
    const int wn   = w >> 1;
    const int lrow = l & 15;
    const int kgrp = l >> 4;
    const int ar   = wm * 16 + lrow;

    f32x4 acc4[4];
    #pragma unroll
    for (int t = 0; t < 4; ++t) acc4[t] = (f32x4){0.f, 0.f, 0.f, 0.f};

    #pragma unroll
    for (int step = 0; step < 8; ++step) {
        const int slot = step * 4 + kgrp;
        bf16x8 a = *(const bf16x8*)&catS[ar * 256 + ((slot ^ (ar & 7)) << 3)];
        #pragma unroll
        for (int t = 0; t < 4; ++t) {
            const int n = wn * 64 + t * 16 + lrow;
            bf16x8 b = *(const bf16x8*)(WB + ((slot * 128 + n) << 3));
            acc4[t] = __builtin_amdgcn_mfma_f32_16x16x32_bf16(a, b, acc4[t], 0, 0, 0);
        }
    }

    // ---- epilogue: bank-padded LDS restage + coalesced stores ----
    __syncthreads();   // all MFMA reads of catS done
    const int cbase = wn * 64 + lrow;                    // D: col=l&15, row=(l>>4)*4+j
    if (mode) {
        unsigned short* lbf = (unsigned short*)smem;            // [32][132] pad
        unsigned char*  lr8 = (unsigned char*)(smem + 8448);    // [32][136] pad
        #pragma unroll
        for (int t = 0; t < 4; ++t) {
            const int col = cbase + t * 16;
            const float bb = bias[col];
            #pragma unroll
            for (int j = 0; j < 4; ++j) {
                float v = fmaxf(acc4[t][j] + bb, 0.0f);
                const int row = wm * 16 + kgrp * 4 + j;
                lbf[row * 132 + col] = (unsigned short)f2bf(v);
                lr8[row * 136 + col] = f2fp8(v);
            }
        }
        __syncthreads();
        #pragma unroll
        for (int it = 0; it < 8; ++it) {
            const int row = w * 8 + it;
            unsigned int v = *(const unsigned int*)&lbf[row * 132 + l * 2];
            *(unsigned int*)&outb[(long)(block_row + row) * 128 + l * 2] = v;
        }
        #pragma unroll
        for (int it = 0; it < 4; ++it) {
            const int row = w * 8 + it * 2 + (l >> 5);
            unsigned int v = *(const unsigned int*)&lr8[row * 136 + (l & 31) * 4];
            *(unsigned int*)&outf8[(long)(block_row + row) * 128 + (l & 31) * 4] = v;
        }
    } else {
        float* lf = (float*)smem;                               // [32][132] pad
        #pragma unroll
        for (int t = 0; t < 4; ++t) {
            const int col = cbase + t * 16;
            const float bb = bias[col];
            #pragma unroll
            for (int j = 0; j < 4; ++j) {
                const int row = wm * 16 + kgrp * 4 + j;
                lf[row * 132 + col] = acc4[t][j] + bb;
            }
        }
        __syncthreads();
        #pragma unroll
        for (int it = 0; it < 16; ++it) {
            const int row  = w * 8 + (it >> 1);
            const int half = (it & 1) * 64;
            float v = lf[row * 132 + half + l];
            outf[(long)(block_row + row) * 128 + half + l] = v;
        }
    }
    __syncthreads();   // protect smem reuse before next tile
}

__global__ __launch_bounds__(256, 8) void fused_sage_kernel(
    const unsigned char* __restrict__ f8,
    const unsigned short* __restrict__ selfB,
    const int* __restrict__ rowptr,
    const int* __restrict__ colsrc,
    const unsigned short* __restrict__ WB,
    const float* __restrict__ bias,
    unsigned short* __restrict__ outb,
    unsigned char* __restrict__ outf8,
    float* __restrict__ outf,
    int mode)
{
    __shared__ __align__(16) char smem[20480]; // 16 KB catS + 4 KB eS
    for (int tile = blockIdx.x; tile < NTILE; tile += PGRID)
        process_tile(tile, smem, f8, selfB, rowptr, colsrc, WB, bias,
                     outb, outf8, outf, mode);
}

// ---------------------------------------------------------------------------
extern "C" void kernel_launch(void* const* d_in, const int* in_sizes, int n_in,
                              void* d_out, int out_size, void* d_ws, size_t ws_size,
                              hipStream_t stream)
{
    const float* x   = (const float*)d_in[0];
    const int*   ei  = (const int*)d_in[1];
    const float* W1l = (const float*)d_in[2];
    const float* b1  = (const float*)d_in[3];
    const float* W1r = (const float*)d_in[4];
    const float* W2l = (const float*)d_in[5];
    const float* b2  = (const float*)d_in[6];
    const float* W2r = (const float*)d_in[7];
    float* out = (float*)d_out;

    const int* src = ei;
    const int* dst = ei + N_EDGES;

    int* wsi = (int*)d_ws;
    int* rowptr = wsi + OFF_ROWPTR;
    int* bcnt   = wsi + OFF_BCNT;
    int* bbase  = wsi + OFF_BBASE;
    int* cntM   = wsi + OFF_CNTM;
    unsigned int* pairs = (unsigned int*)(wsi + OFF_PAIRS);
    int* colsrc = wsi + OFF_COLSRC;
    unsigned short* hb  = (unsigned short*)(wsi + OFF_HB);
    unsigned char*  hf8 = (unsigned char*)(wsi + OFF_HF8);
    unsigned short* WB  = (unsigned short*)(wsi + OFF_WB);

    // xf8 (12.8MB) + xb (25.6MB) live in d_out (51.2MB), dead before layer-2
    // overwrites d_out with the f32 output.
    unsigned char*  xf8 = (unsigned char*)d_out;
    unsigned short* xb  = (unsigned short*)(xf8 + (size_t)N_NODES * DIM);

    conv_pack_kernel<<<6506 + NBLK, 256, 0, stream>>>(
        x, xf8, xb, W1l, W1r, W2l, W2r, WB, dst, cntM);
    colsum_kernel<<<NB, 256, 0, stream>>>(cntM, bcnt);
    bscan_kernel<<<1, 1024, 0, stream>>>(bcnt, bbase, rowptr);
    colprefix_kernel<<<NB, 256, 0, stream>>>(cntM, bbase);
    bfill_kernel<<<NBLK, 256, 0, stream>>>(src, dst, cntM, pairs);
    bucket_csr_kernel<<<NB, 256, 0, stream>>>(pairs, bcnt, bbase, rowptr, colsrc);

    // layer 1: gather fp8(x), self bf16 x -> hb bf16 + hf8 fp8 (relu)
    fused_sage_kernel<<<PGRID, 256, 0, stream>>>(
        xf8, xb, rowptr, colsrc, WB, b1, hb, hf8, (float*)nullptr, 1);
    // layer 2: gather fp8(h), self bf16 h -> out f32
    fused_sage_kernel<<<PGRID, 256, 0, stream>>>(
        hf8, hb, rowptr, colsrc, WB + 32768, b2,
        (unsigned short*)nullptr, (unsigned char*)nullptr, out, 0);
}

// Round 15
// 207.046 us; speedup vs baseline: 2.6372x; 1.3007x over previous
//
#include <hip/hip_runtime.h>
#include <hip/hip_bf16.h>

#define N_NODES 100000
#define N_EDGES 1600000
#define DIM 128
#define BR 32
#define ESTG 1024   // LDS edge-stage capacity (span ~Poisson(512); fallback covers >1024)
#define NB 782      // buckets of 128 nodes
#define CHUNK 4096  // edges per binning block
#define NBLK 391    // ceil(E / CHUNK)

typedef __attribute__((ext_vector_type(8))) short bf16x8;
typedef __attribute__((ext_vector_type(4))) float f32x4;
typedef __attribute__((ext_vector_type(2))) float f32x2;
typedef __attribute__((ext_vector_type(4))) float f4;
typedef __attribute__((ext_vector_type(4))) unsigned int u32x4;
typedef __attribute__((ext_vector_type(2))) unsigned int u32x2;
typedef __attribute__((ext_vector_type(4))) int i32x4;

// ---------------- workspace layout (int units) -----------------------------
#define OFF_ROWPTR 0
#define OFF_BCNT   (N_NODES + 4)
#define OFF_BBASE  (OFF_BCNT + NB)
#define OFF_CNTM   (OFF_BBASE + NB)                 // [NBLK][NB] counts->offsets
#define OFF_PAIRS  (OFF_CNTM + NBLK * NB)
#define OFF_COLSRC (OFF_PAIRS + N_EDGES)
#define OFF_HB     (OFF_COLSRC + N_EDGES)
#define OFF_HF8    (OFF_HB + N_NODES * DIM / 2)
#define OFF_WB     (OFF_HF8 + N_NODES * DIM / 4)

// round-to-nearest-even f32 -> bf16 bits
__device__ inline unsigned int f2bf(float f) {
    unsigned int u = __float_as_uint(f);
    return (u + 0x7FFFu + ((u >> 16) & 1u)) >> 16;
}
__device__ inline unsigned char f2fp8(float v) {
    return (unsigned char)(__builtin_amdgcn_cvt_pk_fp8_f32(v, v, 0u, false) & 0xFFu);
}

// ---------------------------------------------------------------------------
// Merged streaming prep: [0,6250) x -> fp8 + bf16; [6250,6506) pack weights;
// [6506,6506+NBLK) per-chunk bucket histogram -> cntM rows + bcnt totals.
// ---------------------------------------------------------------------------
__global__ __launch_bounds__(256) void conv_pack_kernel(
    const float* __restrict__ x, unsigned char* __restrict__ xf8,
    unsigned short* __restrict__ xb,
    const float* __restrict__ W1l, const float* __restrict__ W1r,
    const float* __restrict__ W2l, const float* __restrict__ W2r,
    unsigned short* __restrict__ WB,
    const int* __restrict__ dst, int* __restrict__ cntM,
    int* __restrict__ bcnt)
{
    __shared__ int histL[NB];
    const int b = blockIdx.x;
    const int tid = threadIdx.x;
    if (b < 6250) {
        long i = (long)(b * 256 + tid) * 8;
        f4 a = __builtin_nontemporal_load((const f4*)(x + i));
        f4 c = __builtin_nontemporal_load((const f4*)(x + i + 4));
        unsigned int w0 = 0, w1 = 0;
        w0 = __builtin_amdgcn_cvt_pk_fp8_f32(a[0], a[1], w0, false);
        w0 = __builtin_amdgcn_cvt_pk_fp8_f32(a[2], a[3], w0, true);
        w1 = __builtin_amdgcn_cvt_pk_fp8_f32(c[0], c[1], w1, false);
        w1 = __builtin_amdgcn_cvt_pk_fp8_f32(c[2], c[3], w1, true);
        u32x2 o8; o8[0] = w0; o8[1] = w1;
        __builtin_nontemporal_store(o8, (u32x2*)(xf8 + i));
        u32x4 ob;
        ob[0] = f2bf(a[0]) | (f2bf(a[1]) << 16);
        ob[1] = f2bf(a[2]) | (f2bf(a[3]) << 16);
        ob[2] = f2bf(c[0]) | (f2bf(c[1]) << 16);
        ob[3] = f2bf(c[2]) | (f2bf(c[3]) << 16);
        __builtin_nontemporal_store(ob, (u32x4*)(xb + i));
    } else if (b < 6506) {
        int t = (b - 6250) * 256 + tid;           // < 65536
        int layer = t >> 15;
        int rest  = t & 32767;
        int half  = rest >> 14;
        int idx   = rest & 16383;
        int k = idx >> 7;
        int n = idx & 127;
        const float* W = layer ? (half ? W2r : W2l) : (half ? W1r : W1l);
        int kk = half * 128 + k;
        WB[layer * 32768 + (((kk >> 3) * 128 + n) << 3) + (kk & 7)] =
            (unsigned short)f2bf(W[idx]);
    } else {
        const int blk = b - 6506;
        const int e0 = blk * CHUNK;
        const int e1 = min(e0 + CHUNK, N_EDGES);
        for (int q = tid; q < NB; q += 256) histL[q] = 0;
        __syncthreads();
        for (int i = (e0 >> 2) + tid; i < (e1 >> 2); i += 256) {
            i32x4 d = __builtin_nontemporal_load((const i32x4*)dst + i);
            atomicAdd(&histL[d[0] >> 7], 1);
            atomicAdd(&histL[d[1] >> 7], 1);
            atomicAdd(&histL[d[2] >> 7], 1);
            atomicAdd(&histL[d[3] >> 7], 1);
        }
        __syncthreads();
        for (int q = tid; q < NB; q += 256) {
            int c = histL[q];
            cntM[blk * NB + q] = c;
            if (c) atomicAdd(&bcnt[q], c);     // replaces colsum kernel
        }
    }
}

// ---------------------------------------------------------------------------
// K2b: exclusive scan of bucket counts -> bbase; rowptr[N]=E.
// ---------------------------------------------------------------------------
__global__ __launch_bounds__(1024) void bscan_kernel(
    const int* __restrict__ bcnt, int* __restrict__ bbase,
    int* __restrict__ rowptr)
{
    __shared__ int tmp[1024];
    int tid = threadIdx.x;
    int v = (tid < NB) ? bcnt[tid] : 0;
    tmp[tid] = v;
    __syncthreads();
    for (int off = 1; off < 1024; off <<= 1) {
        int t = (tid >= off) ? tmp[tid - off] : 0;
        __syncthreads();
        tmp[tid] += t;
        __syncthreads();
    }
    if (tid < NB) bbase[tid] = tmp[tid] - v;
    if (tid == 0) rowptr[N_NODES] = N_EDGES;
}

// ---------------------------------------------------------------------------
// K2c: per-bucket prefix over blocks: cntM[i][b] -> bbase[b] + excl prefix.
// ---------------------------------------------------------------------------
__global__ __launch_bounds__(256) void colprefix_kernel(
    int* __restrict__ cntM, const int* __restrict__ bbase)
{
    __shared__ int e0[512];
    __shared__ int tmp[256];
    const int b = blockIdx.x;
    const int tid = threadIdx.x;
    int a0 = (2 * tid     < NBLK) ? cntM[(2 * tid)     * NB + b] : 0;
    int a1 = (2 * tid + 1 < NBLK) ? cntM[(2 * tid + 1) * NB + b] : 0;
    tmp[tid] = a0 + a1;
    __syncthreads();
    for (int off = 1; off < 256; off <<= 1) {
        int t = (tid >= off) ? tmp[tid - off] : 0;
        __syncthreads();
        tmp[tid] += t;
        __syncthreads();
    }
    int ex = tmp[tid] - (a0 + a1);
    e0[2 * tid] = ex;
    e0[2 * tid + 1] = ex + a0;
    __syncthreads();
    const int base = bbase[b];
    if (2 * tid < NBLK)     cntM[(2 * tid)     * NB + b] = base + e0[2 * tid];
    if (2 * tid + 1 < NBLK) cntM[(2 * tid + 1) * NB + b] = base + e0[2 * tid + 1];
}

// ---------------------------------------------------------------------------
// K3: single-pass binning: LDS rank + precomputed offsets (no global atomics).
// ---------------------------------------------------------------------------
__global__ __launch_bounds__(256) void bfill_kernel(
    const int* __restrict__ src, const int* __restrict__ dst,
    const int* __restrict__ cntM, unsigned int* __restrict__ pairs)
{
    __shared__ int histL[NB];
    __shared__ int baseL[NB];
    const int tid = threadIdx.x;
    const int blk = blockIdx.x;
    const int e0 = blk * CHUNK;
    const int e1 = min(e0 + CHUNK, N_EDGES);
    for (int b = tid; b < NB; b += 256) {
        baseL[b] = cntM[blk * NB + b];
        histL[b] = 0;
    }
    __syncthreads();
    for (int i = (e0 >> 2) + tid; i < (e1 >> 2); i += 256) {
        i32x4 s = __builtin_nontemporal_load((const i32x4*)src + i);
        i32x4 d = __builtin_nontemporal_load((const i32x4*)dst + i);
        #pragma unroll
        for (int k = 0; k < 4; ++k) {
            int bk = d[k] >> 7;
            int r = atomicAdd(&histL[bk], 1);
            pairs[baseL[bk] + r] =
                (unsigned int)s[k] | ((unsigned int)(d[k] & 127) << 25);
        }
    }
}

// ---------------------------------------------------------------------------
// K4: per-bucket exact CSR (128-node LDS hist + scan + LDS tickets).
// ---------------------------------------------------------------------------
__global__ __launch_bounds__(256) void bucket_csr_kernel(
    const unsigned int* __restrict__ pairs,
    const int* __restrict__ bcnt, const int* __restrict__ bbase,
    int* __restrict__ rowptr, int* __restrict__ colsrc)
{
    __shared__ int histA[128], exclS[128], hist2[128];
    const int bucket = blockIdx.x;
    const int tid = threadIdx.x;
    const int cnt  = bcnt[bucket];
    const int base = bbase[bucket];
    if (tid < 128) { histA[tid] = 0; hist2[tid] = 0; }
    __syncthreads();
    for (int i = tid; i < cnt; i += 256)
        atomicAdd(&histA[pairs[base + i] >> 25], 1);
    __syncthreads();
    int v = 0;
    if (tid < 128) { v = histA[tid]; exclS[tid] = v; }
    __syncthreads();
    for (int off = 1; off < 128; off <<= 1) {
        int t = 0;
        if (tid < 128 && tid >= off) t = exclS[tid - off];
        __syncthreads();
        if (tid < 128) exclS[tid] += t;
        __syncthreads();
    }
    if (tid < 128) exclS[tid] -= v;    // exclusive
    const int node0 = bucket * 128;
    if (tid < 128 && node0 + tid < N_NODES)
        rowptr[node0 + tid] = base + exclS[tid];
    __syncthreads();
    for (int i = tid; i < cnt; i += 256) {
        unsigned int p = pairs[base + i];
        int dl = (int)(p >> 25);
        int r = atomicAdd(&hist2[dl], 1);
        colsrc[base + exclS[dl] + r] = (int)(p & 0x1FFFFFFu);
    }
}

// ---------------------------------------------------------------------------
// Fused SAGE layer (r12, best measured): gather-mean from FP8 table (cached),
// bf16 self (nt); [agg|self] @ WB via mfma_f32_16x16x32_bf16; bank-padded
// LDS restage + coalesced stores. LDS 20 KB -> 8 blocks/CU.
// ---------------------------------------------------------------------------
__device__ inline void addfp8(float* acc, u32x2 v) {
    f32x2 p;
    p = __builtin_amdgcn_cvt_pk_f32_fp8((int)v[0], false); acc[0] += p[0]; acc[1] += p[1];
    p = __builtin_amdgcn_cvt_pk_f32_fp8((int)v[0], true);  acc[2] += p[0]; acc[3] += p[1];
    p = __builtin_amdgcn_cvt_pk_f32_fp8((int)v[1], false); acc[4] += p[0]; acc[5] += p[1];
    p = __builtin_amdgcn_cvt_pk_f32_fp8((int)v[1], true);  acc[6] += p[0]; acc[7] += p[1];
}

__global__ __launch_bounds__(256, 8) void fused_sage_kernel(
    const unsigned char* __restrict__ f8,      // fp8 gather table [N][128]
    const unsigned short* __restrict__ selfB,  // bf16 self rows [N][128]
    const int* __restrict__ rowptr,
    const int* __restrict__ colsrc,
    const unsigned short* __restrict__ WB,     // fragment-major [256][128] bf16
    const float* __restrict__ bias,
    unsigned short* __restrict__ outb,         // mode 1: bf16 out (relu)
    unsigned char* __restrict__ outf8,         // mode 1: fp8 out (relu)
    float* __restrict__ outf,                  // mode 0: f32 out
    int mode)
{
    __shared__ __align__(16) char smem[20480]; // 16 KB catS + 4 KB eS
    unsigned short* catS = (unsigned short*)smem;  // [32][256] bf16, XOR swizzle
    int* eS = (int*)(smem + 16384);                // [1024] edge byte-offsets

    const int tid = threadIdx.x;
    const int block_row = blockIdx.x * BR;
    const int ebase = rowptr[block_row];
    const int span  = rowptr[block_row + BR] - ebase;
    const int smax  = span < ESTG ? span : ESTG;

    for (int i = tid; i < smax; i += 256)
        eS[i] = __builtin_nontemporal_load(&colsrc[ebase + i]) << 7;
    __syncthreads();

    const int c   = tid & 15;                  // slot within row
    const int c8  = c * 8;
    const int grp = tid >> 4;                  // 16 gather groups

    #pragma unroll
    for (int it = 0; it < 2; ++it) {
        const int nl = grp * 2 + it;
        const int node = block_row + nl;
        const int s  = rowptr[node] - ebase;
        const int e_ = rowptr[node + 1] - ebase;
        const int lim = e_ < ESTG ? e_ : ESTG;

        // self row (bf16): issue early, consumed at the end
        const u32x4 sv = __builtin_nontemporal_load(
            (const u32x4*)(selfB + ((long)node << 7) + c8));

        float acc[8];
        #pragma unroll
        for (int q = 0; q < 8; ++q) acc[q] = 0.0f;

        int i = s;
        for (; i + 8 <= lim; i += 8) {
            const u32x2 v0 = *(const u32x2*)(f8 + eS[i + 0] + c8);
            const u32x2 v1 = *(const u32x2*)(f8 + eS[i + 1] + c8);
            const u32x2 v2 = *(const u32x2*)(f8 + eS[i + 2] + c8);
            const u32x2 v3 = *(const u32x2*)(f8 + eS[i + 3] + c8);
            const u32x2 v4 = *(const u32x2*)(f8 + eS[i + 4] + c8);
            const u32x2 v5 = *(const u32x2*)(f8 + eS[i + 5] + c8);
            const u32x2 v6 = *(const u32x2*)(f8 + eS[i + 6] + c8);
            const u32x2 v7 = *(const u32x2*)(f8 + eS[i + 7] + c8);
            addfp8(acc, v0); addfp8(acc, v1); addfp8(acc, v2); addfp8(acc, v3);
            addfp8(acc, v4); addfp8(acc, v5); addfp8(acc, v6); addfp8(acc, v7);
        }
        if (i + 4 <= lim) {
            const u32x2 v0 = *(const u32x2*)(f8 + eS[i + 0] + c8);
            const u32x2 v1 = *(const u32x2*)(f8 + eS[i + 1] + c8);
            const u32x2 v2 = *(const u32x2*)(f8 + eS[i + 2] + c8);
            const u32x2 v3 = *(const u32x2*)(f8 + eS[i + 3] + c8);
            addfp8(acc, v0); addfp8(acc, v1); addfp8(acc, v2); addfp8(acc, v3);
            i += 4;
        }
        if (i + 2 <= lim) {
            const u32x2 v0 = *(const u32x2*)(f8 + eS[i + 0] + c8);
            const u32x2 v1 = *(const u32x2*)(f8 + eS[i + 1] + c8);
            addfp8(acc, v0); addfp8(acc, v1);
            i += 2;
        }
        if (i < lim) {
            const u32x2 v = *(const u32x2*)(f8 + eS[i] + c8);
            addfp8(acc, v);
            ++i;
        }
        for (; i < e_; ++i) {   // span > ESTG fallback
            const u32x2 v = *(const u32x2*)(f8 + ((long)colsrc[ebase + i] << 7) + c8);
            addfp8(acc, v);
        }

        const float inv = 1.0f / fmaxf((float)(e_ - s), 1.0f);
        uint4 pv;
        pv.x = f2bf(acc[0] * inv) | (f2bf(acc[1] * inv) << 16);
        pv.y = f2bf(acc[2] * inv) | (f2bf(acc[3] * inv) << 16);
        pv.z = f2bf(acc[4] * inv) | (f2bf(acc[5] * inv) << 16);
        pv.w = f2bf(acc[6] * inv) | (f2bf(acc[7] * inv) << 16);
        const int sw = c ^ (nl & 7);
        *(uint4*)&catS[nl * 256 + sw * 8] = pv;                      // agg
        *(u32x4*)&catS[nl * 256 + 128 + sw * 8] = sv;                // self
    }
    __syncthreads();

    // ---- MFMA GEMM: [32,256] @ [256,128] ----
    const int w    = tid >> 6;
    const int l    = tid & 63;
    const int wm   = w & 1;
    const int wn   = w >> 1;
    const int lrow = l & 15;
    const int kgrp = l >> 4;
    const int ar   = wm * 16 + lrow;

    f32x4 acc4[4];
    #pragma unroll
    for (int t = 0; t < 4; ++t) acc4[t] = (f32x4){0.f, 0.f, 0.f, 0.f};

    #pragma unroll
    for (int step = 0; step < 8; ++step) {
        const int slot = step * 4 + kgrp;
        bf16x8 a = *(const bf16x8*)&catS[ar * 256 + ((slot ^ (ar & 7)) << 3)];
        #pragma unroll
        for (int t = 0; t < 4; ++t) {
            const int n = wn * 64 + t * 16 + lrow;
            bf16x8 b = *(const bf16x8*)(WB + ((slot * 128 + n) << 3));
            acc4[t] = __builtin_amdgcn_mfma_f32_16x16x32_bf16(a, b, acc4[t], 0, 0, 0);
        }
    }

    // ---- epilogue: bank-padded LDS restage + coalesced stores ----
    __syncthreads();   // all MFMA reads of catS done
    const int cbase = wn * 64 + lrow;                    // D: col=l&15, row=(l>>4)*4+j
    if (mode) {
        unsigned short* lbf = (unsigned short*)smem;            // [32][132] pad
        unsigned char*  lr8 = (unsigned char*)(smem + 8448);    // [32][136] pad
        #pragma unroll
        for (int t = 0; t < 4; ++t) {
            const int col = cbase + t * 16;
            const float bb = bias[col];
            #pragma unroll
            for (int j = 0; j < 4; ++j) {
                float v = fmaxf(acc4[t][j] + bb, 0.0f);
                const int row = wm * 16 + kgrp * 4 + j;
                lbf[row * 132 + col] = (unsigned short)f2bf(v);
                lr8[row * 136 + col] = f2fp8(v);
            }
        }
        __syncthreads();
        #pragma unroll
        for (int it = 0; it < 8; ++it) {
            const int row = w * 8 + it;
            unsigned int v = *(const unsigned int*)&lbf[row * 132 + l * 2];
            *(unsigned int*)&outb[(long)(block_row + row) * 128 + l * 2] = v;
        }
        #pragma unroll
        for (int it = 0; it < 4; ++it) {
            const int row = w * 8 + it * 2 + (l >> 5);
            unsigned int v = *(const unsigned int*)&lr8[row * 136 + (l & 31) * 4];
            *(unsigned int*)&outf8[(long)(block_row + row) * 128 + (l & 31) * 4] = v;
        }
    } else {
        float* lf = (float*)smem;                               // [32][132] pad
        #pragma unroll
        for (int t = 0; t < 4; ++t) {
            const int col = cbase + t * 16;
            const float bb = bias[col];
            #pragma unroll
            for (int j = 0; j < 4; ++j) {
                const int row = wm * 16 + kgrp * 4 + j;
                lf[row * 132 + col] = acc4[t][j] + bb;
            }
        }
        __syncthreads();
        #pragma unroll
        for (int it = 0; it < 16; ++it) {
            const int row  = w * 8 + (it >> 1);
            const int half = (it & 1) * 64;
            float v = lf[row * 132 + half + l];
            outf[(long)(block_row + row) * 128 + half + l] = v;
        }
    }
}

// ---------------------------------------------------------------------------
extern "C" void kernel_launch(void* const* d_in, const int* in_sizes, int n_in,
                              void* d_out, int out_size, void* d_ws, size_t ws_size,
                              hipStream_t stream)
{
    const float* x   = (const float*)d_in[0];
    const int*   ei  = (const int*)d_in[1];
    const float* W1l = (const float*)d_in[2];
    const float* b1  = (const float*)d_in[3];
    const float* W1r = (const float*)d_in[4];
    const float* W2l = (const float*)d_in[5];
    const float* b2  = (const float*)d_in[6];
    const float* W2r = (const float*)d_in[7];
    float* out = (float*)d_out;

    const int* src = ei;
    const int* dst = ei + N_EDGES;

    int* wsi = (int*)d_ws;
    int* rowptr = wsi + OFF_ROWPTR;
    int* bcnt   = wsi + OFF_BCNT;
    int* bbase  = wsi + OFF_BBASE;
    int* cntM   = wsi + OFF_CNTM;
    unsigned int* pairs = (unsigned int*)(wsi + OFF_PAIRS);
    int* colsrc = wsi + OFF_COLSRC;
    unsigned short* hb  = (unsigned short*)(wsi + OFF_HB);
    unsigned char*  hf8 = (unsigned char*)(wsi + OFF_HF8);
    unsigned short* WB  = (unsigned short*)(wsi + OFF_WB);

    // xf8 (12.8MB) + xb (25.6MB) live in d_out (51.2MB), dead before layer-2
    // overwrites d_out with the f32 output.
    unsigned char*  xf8 = (unsigned char*)d_out;
    unsigned short* xb  = (unsigned short*)(xf8 + (size_t)N_NODES * DIM);

    hipMemsetAsync(bcnt, 0, (size_t)NB * sizeof(int), stream);

    conv_pack_kernel<<<6506 + NBLK, 256, 0, stream>>>(
        x, xf8, xb, W1l, W1r, W2l, W2r, WB, dst, cntM, bcnt);
    bscan_kernel<<<1, 1024, 0, stream>>>(bcnt, bbase, rowptr);
    colprefix_kernel<<<NB, 256, 0, stream>>>(cntM, bbase);
    bfill_kernel<<<NBLK, 256, 0, stream>>>(src, dst, cntM, pairs);
    bucket_csr_kernel<<<NB, 256, 0, stream>>>(pairs, bcnt, bbase, rowptr, colsrc);

    const int gblocks = N_NODES / BR;   // 3125
    // layer 1: gather fp8(x), self bf16 x -> hb bf16 + hf8 fp8 (relu)
    fused_sage_kernel<<<gblocks, 256, 0, stream>>>(
        xf8, xb, rowptr, colsrc, WB, b1, hb, hf8, (float*)nullptr, 1);
    // layer 2: gather fp8(h), self bf16 h -> out f32
    fused_sage_kernel<<<gblocks, 256, 0, stream>>>(
        hf8, hb, rowptr, colsrc, WB + 32768, b2,
        (unsigned short*)nullptr, (unsigned char*)nullptr, out, 0);
}

// Round 16
// 196.048 us; speedup vs baseline: 2.7852x; 1.0561x over previous
//
#include <hip/hip_runtime.h>
#include <hip/hip_bf16.h>

#define N_NODES 100000
#define N_EDGES 1600000
#define DIM 128
#define BR 32
#define ESTG 1024   // LDS edge-stage capacity (span ~Poisson(512); fallback covers >1024)
#define NB 782      // buckets of 128 nodes
#define CHUNK 4096  // edges per binning block
#define NBLK 391    // ceil(E / CHUNK)

typedef __attribute__((ext_vector_type(8))) short bf16x8;
typedef __attribute__((ext_vector_type(4))) float f32x4;
typedef __attribute__((ext_vector_type(2))) float f32x2;
typedef __attribute__((ext_vector_type(4))) float f4;
typedef __attribute__((ext_vector_type(4))) unsigned int u32x4;
typedef __attribute__((ext_vector_type(2))) unsigned int u32x2;
typedef __attribute__((ext_vector_type(4))) int i32x4;

// ---------------- workspace layout (int units) -----------------------------
#define OFF_ROWPTR 0
#define OFF_BCNT   (N_NODES + 4)
#define OFF_BBASE  (OFF_BCNT + NB)
#define OFF_CNTM   (OFF_BBASE + NB)                 // [NBLK][NB] counts->offsets
#define OFF_PAIRS  (OFF_CNTM + NBLK * NB)
#define OFF_COLSRC (OFF_PAIRS + N_EDGES)
#define OFF_HB     (OFF_COLSRC + N_EDGES)
#define OFF_HF8    (OFF_HB + N_NODES * DIM / 2)
#define OFF_WB     (OFF_HF8 + N_NODES * DIM / 4)

// round-to-nearest-even f32 -> bf16 bits
__device__ inline unsigned int f2bf(float f) {
    unsigned int u = __float_as_uint(f);
    return (u + 0x7FFFu + ((u >> 16) & 1u)) >> 16;
}
__device__ inline unsigned char f2fp8(float v) {
    return (unsigned char)(__builtin_amdgcn_cvt_pk_fp8_f32(v, v, 0u, false) & 0xFFu);
}

// ---------------------------------------------------------------------------
// Merged streaming prep: [0,6250) x -> fp8 + bf16; [6250,6506) pack weights;
// [6506,6506+NBLK) per-chunk bucket histogram -> cntM (no global atomics).
// ---------------------------------------------------------------------------
__global__ __launch_bounds__(256) void conv_pack_kernel(
    const float* __restrict__ x, unsigned char* __restrict__ xf8,
    unsigned short* __restrict__ xb,
    const float* __restrict__ W1l, const float* __restrict__ W1r,
    const float* __restrict__ W2l, const float* __restrict__ W2r,
    unsigned short* __restrict__ WB,
    const int* __restrict__ dst, int* __restrict__ cntM)
{
    __shared__ int histL[NB];
    const int b = blockIdx.x;
    const int tid = threadIdx.x;
    if (b < 6250) {
        long i = (long)(b * 256 + tid) * 8;
        f4 a = __builtin_nontemporal_load((const f4*)(x + i));
        f4 c = __builtin_nontemporal_load((const f4*)(x + i + 4));
        unsigned int w0 = 0, w1 = 0;
        w0 = __builtin_amdgcn_cvt_pk_fp8_f32(a[0], a[1], w0, false);
        w0 = __builtin_amdgcn_cvt_pk_fp8_f32(a[2], a[3], w0, true);
        w1 = __builtin_amdgcn_cvt_pk_fp8_f32(c[0], c[1], w1, false);
        w1 = __builtin_amdgcn_cvt_pk_fp8_f32(c[2], c[3], w1, true);
        u32x2 o8; o8[0] = w0; o8[1] = w1;
        __builtin_nontemporal_store(o8, (u32x2*)(xf8 + i));
        u32x4 ob;
        ob[0] = f2bf(a[0]) | (f2bf(a[1]) << 16);
        ob[1] = f2bf(a[2]) | (f2bf(a[3]) << 16);
        ob[2] = f2bf(c[0]) | (f2bf(c[1]) << 16);
        ob[3] = f2bf(c[2]) | (f2bf(c[3]) << 16);
        __builtin_nontemporal_store(ob, (u32x4*)(xb + i));
    } else if (b < 6506) {
        int t = (b - 6250) * 256 + tid;           // < 65536
        int layer = t >> 15;
        int rest  = t & 32767;
        int half  = rest >> 14;
        int idx   = rest & 16383;
        int k = idx >> 7;
        int n = idx & 127;
        const float* W = layer ? (half ? W2r : W2l) : (half ? W1r : W1l);
        int kk = half * 128 + k;
        WB[layer * 32768 + (((kk >> 3) * 128 + n) << 3) + (kk & 7)] =
            (unsigned short)f2bf(W[idx]);
    } else {
        const int blk = b - 6506;
        const int e0 = blk * CHUNK;
        const int e1 = min(e0 + CHUNK, N_EDGES);
        for (int q = tid; q < NB; q += 256) histL[q] = 0;
        __syncthreads();
        for (int i = (e0 >> 2) + tid; i < (e1 >> 2); i += 256) {
            i32x4 d = __builtin_nontemporal_load((const i32x4*)dst + i);
            atomicAdd(&histL[d[0] >> 7], 1);
            atomicAdd(&histL[d[1] >> 7], 1);
            atomicAdd(&histL[d[2] >> 7], 1);
            atomicAdd(&histL[d[3] >> 7], 1);
        }
        __syncthreads();
        for (int q = tid; q < NB; q += 256)
            cntM[blk * NB + q] = histL[q];
    }
}

// ---------------------------------------------------------------------------
// K2a: bucket totals (column sums of cntM).
// ---------------------------------------------------------------------------
__global__ __launch_bounds__(256) void colsum_kernel(
    const int* __restrict__ cntM, int* __restrict__ bcnt)
{
    __shared__ int red[256];
    const int b = blockIdx.x;
    const int tid = threadIdx.x;
    int s = 0;
    for (int i = tid; i < NBLK; i += 256) s += cntM[i * NB + b];
    red[tid] = s;
    __syncthreads();
    for (int off = 128; off > 0; off >>= 1) {
        if (tid < off) red[tid] += red[tid + off];
        __syncthreads();
    }
    if (tid == 0) bcnt[b] = red[0];
}

// ---------------------------------------------------------------------------
// K2b: exclusive scan of bucket counts -> bbase; rowptr[N]=E.
// ---------------------------------------------------------------------------
__global__ __launch_bounds__(1024) void bscan_kernel(
    const int* __restrict__ bcnt, int* __restrict__ bbase,
    int* __restrict__ rowptr)
{
    __shared__ int tmp[1024];
    int tid = threadIdx.x;
    int v = (tid < NB) ? bcnt[tid] : 0;
    tmp[tid] = v;
    __syncthreads();
    for (int off = 1; off < 1024; off <<= 1) {
        int t = (tid >= off) ? tmp[tid - off] : 0;
        __syncthreads();
        tmp[tid] += t;
        __syncthreads();
    }
    if (tid < NB) bbase[tid] = tmp[tid] - v;
    if (tid == 0) rowptr[N_NODES] = N_EDGES;
}

// ---------------------------------------------------------------------------
// K2c: per-bucket prefix over blocks: cntM[i][b] -> bbase[b] + excl prefix.
// ---------------------------------------------------------------------------
__global__ __launch_bounds__(256) void colprefix_kernel(
    int* __restrict__ cntM, const int* __restrict__ bbase)
{
    __shared__ int e0[512];
    __shared__ int tmp[256];
    const int b = blockIdx.x;
    const int tid = threadIdx.x;
    int a0 = (2 * tid     < NBLK) ? cntM[(2 * tid)     * NB + b] : 0;
    int a1 = (2 * tid + 1 < NBLK) ? cntM[(2 * tid + 1) * NB + b] : 0;
    tmp[tid] = a0 + a1;
    __syncthreads();
    for (int off = 1; off < 256; off <<= 1) {
        int t = (tid >= off) ? tmp[tid - off] : 0;
        __syncthreads();
        tmp[tid] += t;
        __syncthreads();
    }
    int ex = tmp[tid] - (a0 + a1);
    e0[2 * tid] = ex;
    e0[2 * tid + 1] = ex + a0;
    __syncthreads();
    const int base = bbase[b];
    if (2 * tid < NBLK)     cntM[(2 * tid)     * NB + b] = base + e0[2 * tid];
    if (2 * tid + 1 < NBLK) cntM[(2 * tid + 1) * NB + b] = base + e0[2 * tid + 1];
}

// ---------------------------------------------------------------------------
// K3: single-pass binning: LDS rank + precomputed offsets (no global atomics).
// ---------------------------------------------------------------------------
__global__ __launch_bounds__(256) void bfill_kernel(
    const int* __restrict__ src, const int* __restrict__ dst,
    const int* __restrict__ cntM, unsigned int* __restrict__ pairs)
{
    __shared__ int histL[NB];
    __shared__ int baseL[NB];
    const int tid = threadIdx.x;
    const int blk = blockIdx.x;
    const int e0 = blk * CHUNK;
    const int e1 = min(e0 + CHUNK, N_EDGES);
    for (int b = tid; b < NB; b += 256) {
        baseL[b] = cntM[blk * NB + b];
        histL[b] = 0;
    }
    __syncthreads();
    for (int i = (e0 >> 2) + tid; i < (e1 >> 2); i += 256) {
        i32x4 s = __builtin_nontemporal_load((const i32x4*)src + i);
        i32x4 d = __builtin_nontemporal_load((const i32x4*)dst + i);
        #pragma unroll
        for (int k = 0; k < 4; ++k) {
            int bk = d[k] >> 7;
            int r = atomicAdd(&histL[bk], 1);
            pairs[baseL[bk] + r] =
                (unsigned int)s[k] | ((unsigned int)(d[k] & 127) << 25);
        }
    }
}

// ---------------------------------------------------------------------------
// K4: per-bucket exact CSR (128-node LDS hist + scan + LDS tickets).
// ---------------------------------------------------------------------------
__global__ __launch_bounds__(256) void bucket_csr_kernel(
    const unsigned int* __restrict__ pairs,
    const int* __restrict__ bcnt, const int* __restrict__ bbase,
    int* __restrict__ rowptr, int* __restrict__ colsrc)
{
    __shared__ int histA[128], exclS[128], hist2[128];
    const int bucket = blockIdx.x;
    const int tid = threadIdx.x;
    const int cnt  = bcnt[bucket];
    const int base = bbase[bucket];
    if (tid < 128) { histA[tid] = 0; hist2[tid] = 0; }
    __syncthreads();
    for (int i = tid; i < cnt; i += 256)
        atomicAdd(&histA[pairs[base + i] >> 25], 1);
    __syncthreads();
    int v = 0;
    if (tid < 128) { v = histA[tid]; exclS[tid] = v; }
    __syncthreads();
    for (int off = 1; off < 128; off <<= 1) {
        int t = 0;
        if (tid < 128 && tid >= off) t = exclS[tid - off];
        __syncthreads();
        if (tid < 128) exclS[tid] += t;
        __syncthreads();
    }
    if (tid < 128) exclS[tid] -= v;    // exclusive
    const int node0 = bucket * 128;
    if (tid < 128 && node0 + tid < N_NODES)
        rowptr[node0 + tid] = base + exclS[tid];
    __syncthreads();
    for (int i = tid; i < cnt; i += 256) {
        unsigned int p = pairs[base + i];
        int dl = (int)(p >> 25);
        int r = atomicAdd(&hist2[dl], 1);
        colsrc[base + exclS[dl] + r] = (int)(p & 0x1FFFFFFu);
    }
}

// ---------------------------------------------------------------------------
// Fused SAGE layer (r12, best measured): gather-mean from FP8 table (cached),
// bf16 self (nt); [agg|self] @ WB via mfma_f32_16x16x32_bf16; bank-padded
// LDS restage + coalesced stores. LDS 20 KB -> 8 blocks/CU.
// ---------------------------------------------------------------------------
__device__ inline void addfp8(float* acc, u32x2 v) {
    f32x2 p;
    p = __builtin_amdgcn_cvt_pk_f32_fp8((int)v[0], false); acc[0] += p[0]; acc[1] += p[1];
    p = __builtin_amdgcn_cvt_pk_f32_fp8((int)v[0], true);  acc[2] += p[0]; acc[3] += p[1];
    p = __builtin_amdgcn_cvt_pk_f32_fp8((int)v[1], false); acc[4] += p[0]; acc[5] += p[1];
    p = __builtin_amdgcn_cvt_pk_f32_fp8((int)v[1], true);  acc[6] += p[0]; acc[7] += p[1];
}

__global__ __launch_bounds__(256, 8) void fused_sage_kernel(
    const unsigned char* __restrict__ f8,      // fp8 gather table [N][128]
    const unsigned short* __restrict__ selfB,  // bf16 self rows [N][128]
    const int* __restrict__ rowptr,
    const int* __restrict__ colsrc,
    const unsigned short* __restrict__ WB,     // fragment-major [256][128] bf16
    const float* __restrict__ bias,
    unsigned short* __restrict__ outb,         // mode 1: bf16 out (relu)
    unsigned char* __restrict__ outf8,         // mode 1: fp8 out (relu)
    float* __restrict__ outf,                  // mode 0: f32 out
    int mode)
{
    __shared__ __align__(16) char smem[20480]; // 16 KB catS + 4 KB eS
    unsigned short* catS = (unsigned short*)smem;  // [32][256] bf16, XOR swizzle
    int* eS = (int*)(smem + 16384);                // [1024] edge byte-offsets

    const int tid = threadIdx.x;
    const int block_row = blockIdx.x * BR;
    const int ebase = rowptr[block_row];
    const int span  = rowptr[block_row + BR] - ebase;
    const int smax  = span < ESTG ? span : ESTG;

    for (int i = tid; i < smax; i += 256)
        eS[i] = __builtin_nontemporal_load(&colsrc[ebase + i]) << 7;
    __syncthreads();

    const int c   = tid & 15;                  // slot within row
    const int c8  = c * 8;
    const int grp = tid >> 4;                  // 16 gather groups

    #pragma unroll
    for (int it = 0; it < 2; ++it) {
        const int nl = grp * 2 + it;
        const int node = block_row + nl;
        const int s  = rowptr[node] - ebase;
        const int e_ = rowptr[node + 1] - ebase;
        const int lim = e_ < ESTG ? e_ : ESTG;

        // self row (bf16): issue early, consumed at the end
        const u32x4 sv = __builtin_nontemporal_load(
            (const u32x4*)(selfB + ((long)node << 7) + c8));

        float acc[8];
        #pragma unroll
        for (int q = 0; q < 8; ++q) acc[q] = 0.0f;

        int i = s;
        for (; i + 8 <= lim; i += 8) {
            const u32x2 v0 = *(const u32x2*)(f8 + eS[i + 0] + c8);
            const u32x2 v1 = *(const u32x2*)(f8 + eS[i + 1] + c8);
            const u32x2 v2 = *(const u32x2*)(f8 + eS[i + 2] + c8);
            const u32x2 v3 = *(const u32x2*)(f8 + eS[i + 3] + c8);
            const u32x2 v4 = *(const u32x2*)(f8 + eS[i + 4] + c8);
            const u32x2 v5 = *(const u32x2*)(f8 + eS[i + 5] + c8);
            const u32x2 v6 = *(const u32x2*)(f8 + eS[i + 6] + c8);
            const u32x2 v7 = *(const u32x2*)(f8 + eS[i + 7] + c8);
            addfp8(acc, v0); addfp8(acc, v1); addfp8(acc, v2); addfp8(acc, v3);
            addfp8(acc, v4); addfp8(acc, v5); addfp8(acc, v6); addfp8(acc, v7);
        }
        if (i + 4 <= lim) {
            const u32x2 v0 = *(const u32x2*)(f8 + eS[i + 0] + c8);
            const u32x2 v1 = *(const u32x2*)(f8 + eS[i + 1] + c8);
            const u32x2 v2 = *(const u32x2*)(f8 + eS[i + 2] + c8);
            const u32x2 v3 = *(const u32x2*)(f8 + eS[i + 3] + c8);
            addfp8(acc, v0); addfp8(acc, v1); addfp8(acc, v2); addfp8(acc, v3);
            i += 4;
        }
        if (i + 2 <= lim) {
            const u32x2 v0 = *(const u32x2*)(f8 + eS[i + 0] + c8);
            const u32x2 v1 = *(const u32x2*)(f8 + eS[i + 1] + c8);
            addfp8(acc, v0); addfp8(acc, v1);
            i += 2;
        }
        if (i < lim) {
            const u32x2 v = *(const u32x2*)(f8 + eS[i] + c8);
            addfp8(acc, v);
            ++i;
        }
        for (; i < e_; ++i) {   // span > ESTG fallback
            const u32x2 v = *(const u32x2*)(f8 + ((long)colsrc[ebase + i] << 7) + c8);
            addfp8(acc, v);
        }

        const float inv = 1.0f / fmaxf((float)(e_ - s), 1.0f);
        uint4 pv;
        pv.x = f2bf(acc[0] * inv) | (f2bf(acc[1] * inv) << 16);
        pv.y = f2bf(acc[2] * inv) | (f2bf(acc[3] * inv) << 16);
        pv.z = f2bf(acc[4] * inv) | (f2bf(acc[5] * inv) << 16);
        pv.w = f2bf(acc[6] * inv) | (f2bf(acc[7] * inv) << 16);
        const int sw = c ^ (nl & 7);
        *(uint4*)&catS[nl * 256 + sw * 8] = pv;                      // agg
        *(u32x4*)&catS[nl * 256 + 128 + sw * 8] = sv;                // self
    }
    __syncthreads();

    // ---- MFMA GEMM: [32,256] @ [256,128] ----
    const int w    = tid >> 6;
    const int l    = tid & 63;
    const int wm   = w & 1;
    const int wn   = w >> 1;
    const int lrow = l & 15;
    const int kgrp = l >> 4;
    const int ar   = wm * 16 + lrow;

    f32x4 acc4[4];
    #pragma unroll
    for (int t = 0; t < 4; ++t) acc4[t] = (f32x4){0.f, 0.f, 0.f, 0.f};

    #pragma unroll
    for (int step = 0; step < 8; ++step) {
        const int slot = step * 4 + kgrp;
        bf16x8 a = *(const bf16x8*)&catS[ar * 256 + ((slot ^ (ar & 7)) << 3)];
        #pragma unroll
        for (int t = 0; t < 4; ++t) {
            const int n = wn * 64 + t * 16 + lrow;
            bf16x8 b = *(const bf16x8*)(WB + ((slot * 128 + n) << 3));
            acc4[t] = __builtin_amdgcn_mfma_f32_16x16x32_bf16(a, b, acc4[t], 0, 0, 0);
        }
    }

    // ---- epilogue: bank-padded LDS restage + coalesced stores ----
    __syncthreads();   // all MFMA reads of catS done
    const int cbase = wn * 64 + lrow;                    // D: col=l&15, row=(l>>4)*4+j
    if (mode) {
        unsigned short* lbf = (unsigned short*)smem;            // [32][132] pad
        unsigned char*  lr8 = (unsigned char*)(smem + 8448);    // [32][136] pad
        #pragma unroll
        for (int t = 0; t < 4; ++t) {
            const int col = cbase + t * 16;
            const float bb = bias[col];
            #pragma unroll
            for (int j = 0; j < 4; ++j) {
                float v = fmaxf(acc4[t][j] + bb, 0.0f);
                const int row = wm * 16 + kgrp * 4 + j;
                lbf[row * 132 + col] = (unsigned short)f2bf(v);
                lr8[row * 136 + col] = f2fp8(v);
            }
        }
        __syncthreads();
        #pragma unroll
        for (int it = 0; it < 8; ++it) {
            const int row = w * 8 + it;
            unsigned int v = *(const unsigned int*)&lbf[row * 132 + l * 2];
            *(unsigned int*)&outb[(long)(block_row + row) * 128 + l * 2] = v;
        }
        #pragma unroll
        for (int it = 0; it < 4; ++it) {
            const int row = w * 8 + it * 2 + (l >> 5);
            unsigned int v = *(const unsigned int*)&lr8[row * 136 + (l & 31) * 4];
            *(unsigned int*)&outf8[(long)(block_row + row) * 128 + (l & 31) * 4] = v;
        }
    } else {
        float* lf = (float*)smem;                               // [32][132] pad
        #pragma unroll
        for (int t = 0; t < 4; ++t) {
            const int col = cbase + t * 16;
            const float bb = bias[col];
            #pragma unroll
            for (int j = 0; j < 4; ++j) {
                const int row = wm * 16 + kgrp * 4 + j;
                lf[row * 132 + col] = acc4[t][j] + bb;
            }
        }
        __syncthreads();
        #pragma unroll
        for (int it = 0; it < 16; ++it) {
            const int row  = w * 8 + (it >> 1);
            const int half = (it & 1) * 64;
            float v = lf[row * 132 + half + l];
            outf[(long)(block_row + row) * 128 + half + l] = v;
        }
    }
}

// ---------------------------------------------------------------------------
extern "C" void kernel_launch(void* const* d_in, const int* in_sizes, int n_in,
                              void* d_out, int out_size, void* d_ws, size_t ws_size,
                              hipStream_t stream)
{
    const float* x   = (const float*)d_in[0];
    const int*   ei  = (const int*)d_in[1];
    const float* W1l = (const float*)d_in[2];
    const float* b1  = (const float*)d_in[3];
    const float* W1r = (const float*)d_in[4];
    const float* W2l = (const float*)d_in[5];
    const float* b2  = (const float*)d_in[6];
    const float* W2r = (const float*)d_in[7];
    float* out = (float*)d_out;

    const int* src = ei;
    const int* dst = ei + N_EDGES;

    int* wsi = (int*)d_ws;
    int* rowptr = wsi + OFF_ROWPTR;
    int* bcnt   = wsi + OFF_BCNT;
    int* bbase  = wsi + OFF_BBASE;
    int* cntM   = wsi + OFF_CNTM;
    unsigned int* pairs = (unsigned int*)(wsi + OFF_PAIRS);
    int* colsrc = wsi + OFF_COLSRC;
    unsigned short* hb  = (unsigned short*)(wsi + OFF_HB);
    unsigned char*  hf8 = (unsigned char*)(wsi + OFF_HF8);
    unsigned short* WB  = (unsigned short*)(wsi + OFF_WB);

    // xf8 (12.8MB) + xb (25.6MB) live in d_out (51.2MB), dead before layer-2
    // overwrites d_out with the f32 output.
    unsigned char*  xf8 = (unsigned char*)d_out;
    unsigned short* xb  = (unsigned short*)(xf8 + (size_t)N_NODES * DIM);

    conv_pack_kernel<<<6506 + NBLK, 256, 0, stream>>>(
        x, xf8, xb, W1l, W1r, W2l, W2r, WB, dst, cntM);
    colsum_kernel<<<NB, 256, 0, stream>>>(cntM, bcnt);
    bscan_kernel<<<1, 1024, 0, stream>>>(bcnt, bbase, rowptr);
    colprefix_kernel<<<NB, 256, 0, stream>>>(cntM, bbase);
    bfill_kernel<<<NBLK, 256, 0, stream>>>(src, dst, cntM, pairs);
    bucket_csr_kernel<<<NB, 256, 0, stream>>>(pairs, bcnt, bbase, rowptr, colsrc);

    const int gblocks = N_NODES / BR;   // 3125
    // layer 1: gather fp8(x), self bf16 x -> hb bf16 + hf8 fp8 (relu)
    fused_sage_kernel<<<gblocks, 256, 0, stream>>>(
        xf8, xb, rowptr, colsrc, WB, b1, hb, hf8, (float*)nullptr, 1);
    // layer 2: gather fp8(h), self bf16 h -> out f32
    fused_sage_kernel<<<gblocks, 256, 0, stream>>>(
        hf8, hb, rowptr, colsrc, WB + 32768, b2,
        (unsigned short*)nullptr, (unsigned char*)nullptr, out, 0);
}